// Round 5
// baseline (429.794 us; speedup 1.0000x reference)
//
#include <hip/hip_runtime.h>

// SparseSelfAttention, algebraically reduced:
//   out[hd] = sum_g c_g * softmax(Q_hd K_g^T / 16) @ Vs[(2hd-g)%4]
//   Vs[head][j] = sum_{w=-2..2} v[head][(j+2w)%N]
//   c_g = 2 if (hd-g)%4==2 else 1
// N=2304 tokens, 4 heads, dh=64.
//
// k_flash: swapped-operand MFMA (D col = query), max-free softmax (|S|<1),
// fragment-major coalesced K/V, register ping-pong prefetch. Split-K is now
// IN-BLOCK: 4 waves = 4 chunks of 9 tiles; since there is no max-rescaling,
// chunk merge is a plain LDS sum at block end (acc + l), then normalized f16
// partials are written. 1152 blocks -> 4 blocks/CU resident (16 waves/CU) to
// fix R4's 1-wave/SIMD latency starvation at UNCHANGED L2 traffic.

#define N_TOK 2304
#define OUTC 256
#define HSZ (N_TOK * 64)   // halfs per head = 147456

typedef _Float16 half8 __attribute__((ext_vector_type(8)));
typedef _Float16 half4 __attribute__((ext_vector_type(4)));
typedef float f32x4 __attribute__((ext_vector_type(4)));

__device__ __forceinline__ f32x4 mfma16(half8 a, half8 b, f32x4 c) {
  return __builtin_amdgcn_mfma_f32_16x16x32_f16(a, b, c, 0, 0, 0);
}

// ---- kernel 1: fp32 -> fp16 conversion (vectorized x4) ----
__global__ __launch_bounds__(256) void k_convert(
    const float* __restrict__ x, const float* __restrict__ Wq,
    const float* __restrict__ Wk, const float* __restrict__ Wv,
    _Float16* __restrict__ xh, _Float16* __restrict__ Wh) {
  int i = blockIdx.x * 256 + threadIdx.x;
  if (i < N_TOK * OUTC / 4) {
    float4 f = ((const float4*)x)[i];
    half4 h; h[0] = (_Float16)f.x; h[1] = (_Float16)f.y; h[2] = (_Float16)f.z; h[3] = (_Float16)f.w;
    ((half4*)xh)[i] = h;
  }
  if (i < OUTC * OUTC / 4) {
    float4 a = ((const float4*)Wq)[i];
    float4 b = ((const float4*)Wk)[i];
    float4 c = ((const float4*)Wv)[i];
    half4 ha, hb, hc;
    ha[0]=(_Float16)a.x; ha[1]=(_Float16)a.y; ha[2]=(_Float16)a.z; ha[3]=(_Float16)a.w;
    hb[0]=(_Float16)b.x; hb[1]=(_Float16)b.y; hb[2]=(_Float16)b.z; hb[3]=(_Float16)b.w;
    hc[0]=(_Float16)c.x; hc[1]=(_Float16)c.y; hc[2]=(_Float16)c.z; hc[3]=(_Float16)c.w;
    ((half4*)Wh)[i] = ha;
    ((half4*)(Wh + OUTC*OUTC))[i] = hb;
    ((half4*)(Wh + 2*OUTC*OUTC))[i] = hc;
  }
}

// ---- kernel 2: QKV projection ----
// mat 0 -> Qh[hd][n][d] row-major (scaled 1/16)
// mat 1 -> KF fragment-major: KF[hd*HSZ + ((t*4+c)*2+h)*512 + (g4*16+lr)*8 + ii]
//          = K[hd][t*64+16c+lr][32h+8*g4+ii]
// mat 2 -> VfT[o][n] f32 row-major
__global__ __launch_bounds__(256) void k_proj(
    const _Float16* __restrict__ xh, const _Float16* __restrict__ Wh,
    const float* __restrict__ bq, const float* __restrict__ bk,
    const float* __restrict__ bv,
    _Float16* __restrict__ Qh, _Float16* __restrict__ KF, float* __restrict__ VfT) {
  const int w = threadIdx.x >> 6, lane = threadIdx.x & 63;
  const int lr = lane & 15, lk = lane >> 4;
  const int n0 = blockIdx.x * 64 + w * 16;
  const int o0 = blockIdx.y * 64;
  const int mat = blockIdx.z;
  const _Float16* W = Wh + mat * (OUTC * OUTC);
  f32x4 acc[4] = {};
  const _Float16* xrow = xh + (n0 + lr) * OUTC + 8 * lk;
#pragma unroll
  for (int kk = 0; kk < 8; ++kk) {
    half8 a = *(const half8*)(xrow + 32 * kk);
#pragma unroll
    for (int c = 0; c < 4; ++c) {
      half8 b = *(const half8*)(W + (o0 + 16*c + lr) * OUTC + 32*kk + 8*lk);
      acc[c] = mfma16(a, b, acc[c]);
    }
  }
  const float* bias = (mat == 0) ? bq : (mat == 1) ? bk : bv;
  const int hd = blockIdx.y;   // head for mat 0/1
#pragma unroll
  for (int c = 0; c < 4; ++c) {
    int o = o0 + 16*c + lr;
    float bo = bias[o];
    if (mat == 2) {
      float4 vv;
      vv.x = acc[c][0] + bo; vv.y = acc[c][1] + bo;
      vv.z = acc[c][2] + bo; vv.w = acc[c][3] + bo;
      *(float4*)(VfT + (size_t)o * N_TOK + n0 + 4*lk) = vv;
    } else if (mat == 0) {
      int d = 16*c + lr;
#pragma unroll
      for (int r = 0; r < 4; ++r) {
        int n = n0 + 4*lk + r;
        Qh[((size_t)hd * N_TOK + n) * 64 + d] = (_Float16)((acc[c][r] + bo) * 0.0625f);
      }
    } else {
      int d = 16*c + lr;
      int h = d >> 5, g4K = (d >> 3) & 3, iiK = d & 7;
#pragma unroll
      for (int r = 0; r < 4; ++r) {
        int n = n0 + 4*lk + r;
        int tK = n >> 6, cK = (n >> 4) & 3, lrK = n & 15;
        KF[(size_t)hd * HSZ + ((tK*4 + cK)*2 + h)*512 + (g4K*16 + lrK)*8 + iiK] =
            (_Float16)(acc[c][r] + bo);
      }
    }
  }
}

// ---- kernel 3: smooth V over w-shifts, emit fragment-major + k-slot-permuted ----
// VF[vh*HSZ + t*4096 + f*8 + i]  (f = cc*128 + h*64 + g4*16 + lr)
//   = Vs[vh][16cc+lr][ t*64 + 32h + 16*(i>>2) + 4*g4 + (i&3) ]
__global__ __launch_bounds__(256) void k_smooth(
    const float* __restrict__ VfT, _Float16* __restrict__ VF) {
  const int t = blockIdx.x, vh = blockIdx.y;
  for (int f = threadIdx.x; f < 512; f += 256) {
    int cc = f >> 7, h = (f >> 6) & 1, g4 = (f >> 4) & 3, lr = f & 15;
    const float* src = VfT + (size_t)(vh*64 + 16*cc + lr) * N_TOK;
    int jbase = t*64 + 32*h + 4*g4;
    half8 out;
#pragma unroll
    for (int i = 0; i < 8; ++i) {
      int j = jbase + 16*(i >> 2) + (i & 3);
      float s = 0.f;
#pragma unroll
      for (int w = -4; w <= 4; w += 2) s += src[(j + w + N_TOK) % N_TOK];
      out[i] = (_Float16)s;
    }
    *(half8*)(VF + (size_t)vh * HSZ + (size_t)t * 4096 + f * 8) = out;
  }
}

// ---- kernel 4: flash attention, in-block split-K x4 ----
__global__ __launch_bounds__(256, 4) void k_flash(
    const _Float16* __restrict__ Qh, const _Float16* __restrict__ KF,
    const _Float16* __restrict__ VF, _Float16* __restrict__ Opart) {
  __shared__ __align__(16) float Lacc[4][32][68];   // [chunk][q][d], pad 68: 2-way only
  __shared__ float Lsum[4][32];
  const int wv = threadIdx.x >> 6, lane = threadIdx.x & 63;   // wv = K-chunk
  const int lr = lane & 15, g4 = lane >> 4;
  const int n0 = blockIdx.x * 32;
  const int pair = blockIdx.y;                // hd*4 + gk
  const int hd = pair >> 2, gk = pair & 3;
  const int vh = (2*hd + 4 - gk) & 3;

  const _Float16* Qp = Qh + ((size_t)hd * N_TOK + n0 + lr) * 64 + 8*g4;
  const half8 qa0 = *(const half8*)(Qp);
  const half8 qa1 = *(const half8*)(Qp + 32);
  const half8 qb0 = *(const half8*)(Qp + 16*64);
  const half8 qb1 = *(const half8*)(Qp + 16*64 + 32);
  const _Float16* Kb = KF + (size_t)gk * HSZ + lane * 8;
  const _Float16* Vb = VF + (size_t)vh * HSZ + lane * 8;

  f32x4 accA[4] = {}, accB[4] = {};
  float lA = 0.f, lB = 0.f;

  auto loadT = [&](int t, half8 (&k)[8], half8 (&v)[8]) {
#pragma unroll
    for (int c = 0; c < 4; ++c) {
      const _Float16* pk = Kb + (size_t)t*4096 + c*1024;
      k[2*c]   = *(const half8*)(pk);
      k[2*c+1] = *(const half8*)(pk + 512);
      const _Float16* pv = Vb + (size_t)t*4096 + c*1024;
      v[2*c]   = *(const half8*)(pv);
      v[2*c+1] = *(const half8*)(pv + 512);
    }
  };
  auto body = [&](const half8 (&k)[8], const half8 (&v)[8],
                  half8 q0, half8 q1, f32x4 (&acc)[4], float& l_run) {
    f32x4 s[4];
    __builtin_amdgcn_s_setprio(1);
#pragma unroll
    for (int c = 0; c < 4; ++c) {
      f32x4 t = {};
      t = mfma16(k[2*c], q0, t);
      t = mfma16(k[2*c+1], q1, t);
      s[c] = t;  // s[c][r] = S[key 16c+4*g4+r][query lr]
    }
    __builtin_amdgcn_s_setprio(0);
    float p[16], ps = 0.f;
#pragma unroll
    for (int c = 0; c < 4; ++c)
#pragma unroll
      for (int r = 0; r < 4; ++r) {
        float e = __expf(s[c][r]);
        p[4*c + r] = e;
        ps += e;
      }
    l_run += ps;
    half8 pb0, pb1;
#pragma unroll
    for (int ii = 0; ii < 8; ++ii) { pb0[ii] = (_Float16)p[ii]; pb1[ii] = (_Float16)p[8 + ii]; }
    __builtin_amdgcn_s_setprio(1);
#pragma unroll
    for (int cc = 0; cc < 4; ++cc) {
      acc[cc] = mfma16(v[2*cc], pb0, acc[cc]);
      acc[cc] = mfma16(v[2*cc+1], pb1, acc[cc]);
    }
    __builtin_amdgcn_s_setprio(0);
  };

  const int jt0 = wv * 9;
  half8 kA[8], vA[8], kB[8], vB[8];
  loadT(jt0, kA, vA);
#pragma unroll 1
  for (int u = 0; u < 4; ++u) {
    loadT(jt0 + 2*u + 1, kB, vB);
    body(kA, vA, qa0, qa1, accA, lA);
    body(kA, vA, qb0, qb1, accB, lB);
    loadT(jt0 + 2*u + 2, kA, vA);
    body(kB, vB, qa0, qa1, accA, lA);
    body(kB, vB, qb0, qb1, accB, lB);
  }
  body(kA, vA, qa0, qa1, accA, lA);   // tile jt0+8
  body(kA, vA, qb0, qb1, accB, lB);

  // full per-query denom for this chunk
  lA += __shfl_xor(lA, 16); lA += __shfl_xor(lA, 32);
  lB += __shfl_xor(lB, 16); lB += __shfl_xor(lB, 32);

  // dump chunk partials to LDS
#pragma unroll
  for (int cc = 0; cc < 4; ++cc) {
    *(f32x4*)&Lacc[wv][lr][16*cc + 4*g4]      = accA[cc];
    *(f32x4*)&Lacc[wv][16 + lr][16*cc + 4*g4] = accB[cc];
  }
  if (g4 == 0) { Lsum[wv][lr] = lA; Lsum[wv][16 + lr] = lB; }
  __syncthreads();

  // merge 4 chunks (plain sums -- no max rescale exists) and normalize
  const int q = threadIdx.x >> 3, db = (threadIdx.x & 7) * 8;
  float lt = Lsum[0][q] + Lsum[1][q] + Lsum[2][q] + Lsum[3][q];
  float inv = 1.0f / lt;
  half8 o;
#pragma unroll
  for (int i = 0; i < 8; ++i) {
    float s = Lacc[0][q][db+i] + Lacc[1][q][db+i] + Lacc[2][q][db+i] + Lacc[3][q][db+i];
    o[i] = (_Float16)(s * inv);
  }
  *(half8*)(Opart + ((size_t)pair * N_TOK + n0 + q) * 64 + db) = o;
}

// ---- kernel 5: weight by c_g, sum over gk ----
__global__ __launch_bounds__(256) void k_combine(
    const _Float16* __restrict__ Op, float* __restrict__ out) {
  int gid = blockIdx.x * 256 + threadIdx.x;   // 73728 total
  int hd = gid / (N_TOK * 8);
  int rem = gid % (N_TOK * 8);
  int n = rem >> 3, db = (rem & 7) * 8;
  float acc[8] = {};
#pragma unroll
  for (int gk = 0; gk < 4; ++gk) {
    float cg = (((hd - gk) & 3) == 2) ? 2.0f : 1.0f;
    half8 v = *(const half8*)(Op + ((size_t)(hd*4 + gk) * N_TOK + n) * 64 + db);
#pragma unroll
    for (int i = 0; i < 8; ++i) acc[i] += cg * (float)v[i];
  }
  float* dst = out + (size_t)n * OUTC + hd * 64 + db;
  float4 r0, r1;
  r0.x = acc[0]; r0.y = acc[1]; r0.z = acc[2]; r0.w = acc[3];
  r1.x = acc[4]; r1.y = acc[5]; r1.z = acc[6]; r1.w = acc[7];
  *(float4*)(dst)     = r0;
  *(float4*)(dst + 4) = r1;
}

extern "C" void kernel_launch(void* const* d_in, const int* in_sizes, int n_in,
                              void* d_out, int out_size, void* d_ws, size_t ws_size,
                              hipStream_t stream) {
  (void)in_sizes; (void)n_in; (void)out_size; (void)ws_size;
  const float* x  = (const float*)d_in[0];
  const float* Wq = (const float*)d_in[1];
  const float* bq = (const float*)d_in[2];
  const float* Wk = (const float*)d_in[3];
  const float* bk = (const float*)d_in[4];
  const float* Wv = (const float*)d_in[5];
  const float* bv = (const float*)d_in[6];

  char* ws = (char*)d_ws;
  _Float16* xh  = (_Float16*)(ws);              // 1,179,648 B (dead after k_proj)
  _Float16* Wh  = (_Float16*)(ws + 1179648);    //   393,216 B
  _Float16* Qh  = (_Float16*)(ws + 1572864);    // 1,179,648 B
  _Float16* KF  = (_Float16*)(ws + 2752512);    // 1,179,648 B (fragment-major)
  float*    VfT = (float*)   (ws + 3932160);    // 2,359,296 B
  _Float16* VF  = (_Float16*)(ws + 6291456);    // 1,179,648 B (fragment-major)
  _Float16* Op  = (_Float16*)(ws + 7471104);    // 4,718,592 B (ends 12,189,696)
  float* out = (float*)d_out;

  k_convert<<<dim3(576), dim3(256), 0, stream>>>(x, Wq, Wk, Wv, xh, Wh);
  k_proj   <<<dim3(36, 4, 3), dim3(256), 0, stream>>>(xh, Wh, bq, bk, bv, Qh, KF, VfT);
  k_smooth <<<dim3(36, 4), dim3(256), 0, stream>>>(VfT, VF);
  k_flash  <<<dim3(72, 16), dim3(256), 0, stream>>>(Qh, KF, VF, Op);
  k_combine<<<dim3(288), dim3(256), 0, stream>>>(Op, out);
}

// Round 6
// 82.678 us; speedup vs baseline: 5.1984x; 5.1984x over previous
//
#include <hip/hip_runtime.h>

// SparseSelfAttention, algebraically reduced:
//   out[hd] = sum_g c_g * softmax(Q_hd K_g^T / 16) @ Vs[(2hd-g)%4]
//   Vs[head][j] = sum_{w=-2..2} v[head][(j+2w)%N]
//   c_g = 2 if (hd-g)%4==2 else 1
// N=2304 tokens, 4 heads, dh=64.
//
// k_flash: swapped-operand MFMA (D col = query), max-free softmax (|S|<1),
// fragment-major coalesced K/V, register ping-pong prefetch, in-block
// split-K x4 with plain-sum LDS merge (no max rescale exists).
// R5 lesson: __launch_bounds__(256,4) clamped VGPR to 64 -> full spill to
// scratch (FETCH 676MB, WRITE 1.08GB of HBM traffic). Plain (256) gives the
// allocator ~124-140 VGPR (R4-proven, no spill) which still fits 16 waves/CU.

#define N_TOK 2304
#define OUTC 256
#define HSZ (N_TOK * 64)   // halfs per head = 147456

typedef _Float16 half8 __attribute__((ext_vector_type(8)));
typedef _Float16 half4 __attribute__((ext_vector_type(4)));
typedef float f32x4 __attribute__((ext_vector_type(4)));

__device__ __forceinline__ f32x4 mfma16(half8 a, half8 b, f32x4 c) {
  return __builtin_amdgcn_mfma_f32_16x16x32_f16(a, b, c, 0, 0, 0);
}

// ---- kernel 1: fp32 -> fp16 conversion (vectorized x4) ----
__global__ __launch_bounds__(256) void k_convert(
    const float* __restrict__ x, const float* __restrict__ Wq,
    const float* __restrict__ Wk, const float* __restrict__ Wv,
    _Float16* __restrict__ xh, _Float16* __restrict__ Wh) {
  int i = blockIdx.x * 256 + threadIdx.x;
  if (i < N_TOK * OUTC / 4) {
    float4 f = ((const float4*)x)[i];
    half4 h; h[0] = (_Float16)f.x; h[1] = (_Float16)f.y; h[2] = (_Float16)f.z; h[3] = (_Float16)f.w;
    ((half4*)xh)[i] = h;
  }
  if (i < OUTC * OUTC / 4) {
    float4 a = ((const float4*)Wq)[i];
    float4 b = ((const float4*)Wk)[i];
    float4 c = ((const float4*)Wv)[i];
    half4 ha, hb, hc;
    ha[0]=(_Float16)a.x; ha[1]=(_Float16)a.y; ha[2]=(_Float16)a.z; ha[3]=(_Float16)a.w;
    hb[0]=(_Float16)b.x; hb[1]=(_Float16)b.y; hb[2]=(_Float16)b.z; hb[3]=(_Float16)b.w;
    hc[0]=(_Float16)c.x; hc[1]=(_Float16)c.y; hc[2]=(_Float16)c.z; hc[3]=(_Float16)c.w;
    ((half4*)Wh)[i] = ha;
    ((half4*)(Wh + OUTC*OUTC))[i] = hb;
    ((half4*)(Wh + 2*OUTC*OUTC))[i] = hc;
  }
}

// ---- kernel 2: QKV projection ----
// mat 0 -> Qh[hd][n][d] row-major (scaled 1/16)
// mat 1 -> KF fragment-major: KF[hd*HSZ + ((t*4+c)*2+h)*512 + (g4*16+lr)*8 + ii]
//          = K[hd][t*64+16c+lr][32h+8*g4+ii]
// mat 2 -> VfT[o][n] f32 row-major
__global__ __launch_bounds__(256) void k_proj(
    const _Float16* __restrict__ xh, const _Float16* __restrict__ Wh,
    const float* __restrict__ bq, const float* __restrict__ bk,
    const float* __restrict__ bv,
    _Float16* __restrict__ Qh, _Float16* __restrict__ KF, float* __restrict__ VfT) {
  const int w = threadIdx.x >> 6, lane = threadIdx.x & 63;
  const int lr = lane & 15, lk = lane >> 4;
  const int n0 = blockIdx.x * 64 + w * 16;
  const int o0 = blockIdx.y * 64;
  const int mat = blockIdx.z;
  const _Float16* W = Wh + mat * (OUTC * OUTC);
  f32x4 acc[4] = {};
  const _Float16* xrow = xh + (n0 + lr) * OUTC + 8 * lk;
#pragma unroll
  for (int kk = 0; kk < 8; ++kk) {
    half8 a = *(const half8*)(xrow + 32 * kk);
#pragma unroll
    for (int c = 0; c < 4; ++c) {
      half8 b = *(const half8*)(W + (o0 + 16*c + lr) * OUTC + 32*kk + 8*lk);
      acc[c] = mfma16(a, b, acc[c]);
    }
  }
  const float* bias = (mat == 0) ? bq : (mat == 1) ? bk : bv;
  const int hd = blockIdx.y;   // head for mat 0/1
#pragma unroll
  for (int c = 0; c < 4; ++c) {
    int o = o0 + 16*c + lr;
    float bo = bias[o];
    if (mat == 2) {
      float4 vv;
      vv.x = acc[c][0] + bo; vv.y = acc[c][1] + bo;
      vv.z = acc[c][2] + bo; vv.w = acc[c][3] + bo;
      *(float4*)(VfT + (size_t)o * N_TOK + n0 + 4*lk) = vv;
    } else if (mat == 0) {
      int d = 16*c + lr;
#pragma unroll
      for (int r = 0; r < 4; ++r) {
        int n = n0 + 4*lk + r;
        Qh[((size_t)hd * N_TOK + n) * 64 + d] = (_Float16)((acc[c][r] + bo) * 0.0625f);
      }
    } else {
      int d = 16*c + lr;
      int h = d >> 5, g4K = (d >> 3) & 3, iiK = d & 7;
#pragma unroll
      for (int r = 0; r < 4; ++r) {
        int n = n0 + 4*lk + r;
        int tK = n >> 6, cK = (n >> 4) & 3, lrK = n & 15;
        KF[(size_t)hd * HSZ + ((tK*4 + cK)*2 + h)*512 + (g4K*16 + lrK)*8 + iiK] =
            (_Float16)(acc[c][r] + bo);
      }
    }
  }
}

// ---- kernel 3: smooth V over w-shifts, emit fragment-major + k-slot-permuted ----
// VF[vh*HSZ + t*4096 + f*8 + i]  (f = cc*128 + h*64 + g4*16 + lr)
//   = Vs[vh][16cc+lr][ t*64 + 32h + 16*(i>>2) + 4*g4 + (i&3) ]
__global__ __launch_bounds__(256) void k_smooth(
    const float* __restrict__ VfT, _Float16* __restrict__ VF) {
  const int t = blockIdx.x, vh = blockIdx.y;
  for (int f = threadIdx.x; f < 512; f += 256) {
    int cc = f >> 7, h = (f >> 6) & 1, g4 = (f >> 4) & 3, lr = f & 15;
    const float* src = VfT + (size_t)(vh*64 + 16*cc + lr) * N_TOK;
    int jbase = t*64 + 32*h + 4*g4;
    half8 out;
#pragma unroll
    for (int i = 0; i < 8; ++i) {
      int j = jbase + 16*(i >> 2) + (i & 3);
      float s = 0.f;
#pragma unroll
      for (int w = -4; w <= 4; w += 2) s += src[(j + w + N_TOK) % N_TOK];
      out[i] = (_Float16)s;
    }
    *(half8*)(VF + (size_t)vh * HSZ + (size_t)t * 4096 + f * 8) = out;
  }
}

// ---- kernel 4: flash attention, in-block split-K x4 ----
__global__ __launch_bounds__(256) void k_flash(
    const _Float16* __restrict__ Qh, const _Float16* __restrict__ KF,
    const _Float16* __restrict__ VF, _Float16* __restrict__ Opart) {
  __shared__ __align__(16) float Lacc[4][32][68];   // [chunk][q][d], pad 68: 2-way only
  __shared__ float Lsum[4][32];
  const int wv = threadIdx.x >> 6, lane = threadIdx.x & 63;   // wv = K-chunk
  const int lr = lane & 15, g4 = lane >> 4;
  const int n0 = blockIdx.x * 32;
  const int pair = blockIdx.y;                // hd*4 + gk
  const int hd = pair >> 2, gk = pair & 3;
  const int vh = (2*hd + 4 - gk) & 3;

  const _Float16* Qp = Qh + ((size_t)hd * N_TOK + n0 + lr) * 64 + 8*g4;
  const half8 qa0 = *(const half8*)(Qp);
  const half8 qa1 = *(const half8*)(Qp + 32);
  const half8 qb0 = *(const half8*)(Qp + 16*64);
  const half8 qb1 = *(const half8*)(Qp + 16*64 + 32);
  const _Float16* Kb = KF + (size_t)gk * HSZ + lane * 8;
  const _Float16* Vb = VF + (size_t)vh * HSZ + lane * 8;

  f32x4 accA[4] = {}, accB[4] = {};
  float lA = 0.f, lB = 0.f;

  auto loadT = [&](int t, half8 (&k)[8], half8 (&v)[8]) {
#pragma unroll
    for (int c = 0; c < 4; ++c) {
      const _Float16* pk = Kb + (size_t)t*4096 + c*1024;
      k[2*c]   = *(const half8*)(pk);
      k[2*c+1] = *(const half8*)(pk + 512);
      const _Float16* pv = Vb + (size_t)t*4096 + c*1024;
      v[2*c]   = *(const half8*)(pv);
      v[2*c+1] = *(const half8*)(pv + 512);
    }
  };
  auto body = [&](const half8 (&k)[8], const half8 (&v)[8],
                  half8 q0, half8 q1, f32x4 (&acc)[4], float& l_run) {
    f32x4 s[4];
    __builtin_amdgcn_s_setprio(1);
#pragma unroll
    for (int c = 0; c < 4; ++c) {
      f32x4 t = {};
      t = mfma16(k[2*c], q0, t);
      t = mfma16(k[2*c+1], q1, t);
      s[c] = t;  // s[c][r] = S[key 16c+4*g4+r][query lr]
    }
    __builtin_amdgcn_s_setprio(0);
    float p[16], ps = 0.f;
#pragma unroll
    for (int c = 0; c < 4; ++c)
#pragma unroll
      for (int r = 0; r < 4; ++r) {
        float e = __expf(s[c][r]);
        p[4*c + r] = e;
        ps += e;
      }
    l_run += ps;
    half8 pb0, pb1;
#pragma unroll
    for (int ii = 0; ii < 8; ++ii) { pb0[ii] = (_Float16)p[ii]; pb1[ii] = (_Float16)p[8 + ii]; }
    __builtin_amdgcn_s_setprio(1);
#pragma unroll
    for (int cc = 0; cc < 4; ++cc) {
      acc[cc] = mfma16(v[2*cc], pb0, acc[cc]);
      acc[cc] = mfma16(v[2*cc+1], pb1, acc[cc]);
    }
    __builtin_amdgcn_s_setprio(0);
  };

  const int jt0 = wv * 9;
  half8 kA[8], vA[8], kB[8], vB[8];
  loadT(jt0, kA, vA);
#pragma unroll 1
  for (int u = 0; u < 4; ++u) {
    loadT(jt0 + 2*u + 1, kB, vB);
    body(kA, vA, qa0, qa1, accA, lA);
    body(kA, vA, qb0, qb1, accB, lB);
    loadT(jt0 + 2*u + 2, kA, vA);
    body(kB, vB, qa0, qa1, accA, lA);
    body(kB, vB, qb0, qb1, accB, lB);
  }
  body(kA, vA, qa0, qa1, accA, lA);   // tile jt0+8
  body(kA, vA, qb0, qb1, accB, lB);

  // full per-query denom for this chunk
  lA += __shfl_xor(lA, 16); lA += __shfl_xor(lA, 32);
  lB += __shfl_xor(lB, 16); lB += __shfl_xor(lB, 32);

  // dump chunk partials to LDS
#pragma unroll
  for (int cc = 0; cc < 4; ++cc) {
    *(f32x4*)&Lacc[wv][lr][16*cc + 4*g4]      = accA[cc];
    *(f32x4*)&Lacc[wv][16 + lr][16*cc + 4*g4] = accB[cc];
  }
  if (g4 == 0) { Lsum[wv][lr] = lA; Lsum[wv][16 + lr] = lB; }
  __syncthreads();

  // merge 4 chunks (plain sums -- no max rescale exists) and normalize
  const int q = threadIdx.x >> 3, db = (threadIdx.x & 7) * 8;
  float lt = Lsum[0][q] + Lsum[1][q] + Lsum[2][q] + Lsum[3][q];
  float inv = 1.0f / lt;
  half8 o;
#pragma unroll
  for (int i = 0; i < 8; ++i) {
    float s = Lacc[0][q][db+i] + Lacc[1][q][db+i] + Lacc[2][q][db+i] + Lacc[3][q][db+i];
    o[i] = (_Float16)(s * inv);
  }
  *(half8*)(Opart + ((size_t)pair * N_TOK + n0 + q) * 64 + db) = o;
}

// ---- kernel 5: weight by c_g, sum over gk ----
__global__ __launch_bounds__(256) void k_combine(
    const _Float16* __restrict__ Op, float* __restrict__ out) {
  int gid = blockIdx.x * 256 + threadIdx.x;   // 73728 total
  int hd = gid / (N_TOK * 8);
  int rem = gid % (N_TOK * 8);
  int n = rem >> 3, db = (rem & 7) * 8;
  float acc[8] = {};
#pragma unroll
  for (int gk = 0; gk < 4; ++gk) {
    float cg = (((hd - gk) & 3) == 2) ? 2.0f : 1.0f;
    half8 v = *(const half8*)(Op + ((size_t)(hd*4 + gk) * N_TOK + n) * 64 + db);
#pragma unroll
    for (int i = 0; i < 8; ++i) acc[i] += cg * (float)v[i];
  }
  float* dst = out + (size_t)n * OUTC + hd * 64 + db;
  float4 r0, r1;
  r0.x = acc[0]; r0.y = acc[1]; r0.z = acc[2]; r0.w = acc[3];
  r1.x = acc[4]; r1.y = acc[5]; r1.z = acc[6]; r1.w = acc[7];
  *(float4*)(dst)     = r0;
  *(float4*)(dst + 4) = r1;
}

extern "C" void kernel_launch(void* const* d_in, const int* in_sizes, int n_in,
                              void* d_out, int out_size, void* d_ws, size_t ws_size,
                              hipStream_t stream) {
  (void)in_sizes; (void)n_in; (void)out_size; (void)ws_size;
  const float* x  = (const float*)d_in[0];
  const float* Wq = (const float*)d_in[1];
  const float* bq = (const float*)d_in[2];
  const float* Wk = (const float*)d_in[3];
  const float* bk = (const float*)d_in[4];
  const float* Wv = (const float*)d_in[5];
  const float* bv = (const float*)d_in[6];

  char* ws = (char*)d_ws;
  _Float16* xh  = (_Float16*)(ws);              // 1,179,648 B (dead after k_proj)
  _Float16* Wh  = (_Float16*)(ws + 1179648);    //   393,216 B
  _Float16* Qh  = (_Float16*)(ws + 1572864);    // 1,179,648 B
  _Float16* KF  = (_Float16*)(ws + 2752512);    // 1,179,648 B (fragment-major)
  float*    VfT = (float*)   (ws + 3932160);    // 2,359,296 B
  _Float16* VF  = (_Float16*)(ws + 6291456);    // 1,179,648 B (fragment-major)
  _Float16* Op  = (_Float16*)(ws + 7471104);    // 4,718,592 B (ends 12,189,696)
  float* out = (float*)d_out;

  k_convert<<<dim3(576), dim3(256), 0, stream>>>(x, Wq, Wk, Wv, xh, Wh);
  k_proj   <<<dim3(36, 4, 3), dim3(256), 0, stream>>>(xh, Wh, bq, bk, bv, Qh, KF, VfT);
  k_smooth <<<dim3(36, 4), dim3(256), 0, stream>>>(VfT, VF);
  k_flash  <<<dim3(72, 16), dim3(256), 0, stream>>>(Qh, KF, VF, Op);
  k_combine<<<dim3(288), dim3(256), 0, stream>>>(Op, out);
}

// Round 7
// 73.972 us; speedup vs baseline: 5.8102x; 1.1177x over previous
//
#include <hip/hip_runtime.h>

// SparseSelfAttention, algebraically reduced:
//   out[hd] = sum_g c_g * softmax(Q_hd K_g^T / 16) @ Vs[(2hd-g)%4]
//   Vs[head][j] = sum_{w=-2..2} v[head][(j+2w)%N]
//   c_g = 2 if (hd-g)%4==2 else 1
// N=2304 tokens, 4 heads, dh=64.
//
// k_flash v3: K/V tiles live in LDS (global_load_lds width=16, dbuf, one
// barrier per tile -- catalog T3-minimum), SHARED by 4 waves/block. Registers
// hold only Q + accumulators -> VGPR ~90 -> 4 waves/SIMD (R6 lesson: 144 VGPR
// crossed the 128 cliff and halved residency). Softmax: exp2 with log2(e)
// folded into Q scale; denominator via ones-row MFMA (no adds, no shuffles).
// Global split-K x4 merged by k_combine.

#define N_TOK 2304
#define OUTC 256
#define HSZ (N_TOK * 64)   // halfs per head = 147456

typedef _Float16 half8 __attribute__((ext_vector_type(8)));
typedef _Float16 half4 __attribute__((ext_vector_type(4)));
typedef float f32x4 __attribute__((ext_vector_type(4)));

typedef __attribute__((address_space(3))) unsigned int as3_u32;
typedef __attribute__((address_space(1))) unsigned int as1_u32;

__device__ __forceinline__ f32x4 mfma16(half8 a, half8 b, f32x4 c) {
  return __builtin_amdgcn_mfma_f32_16x16x32_f16(a, b, c, 0, 0, 0);
}

__device__ __forceinline__ void gload_lds16(const _Float16* g, _Float16* l) {
  __builtin_amdgcn_global_load_lds((const as1_u32*)g, (as3_u32*)l, 16, 0, 0);
}

// ---- kernel 1: fp32 -> fp16 conversion (vectorized x4) ----
__global__ __launch_bounds__(256) void k_convert(
    const float* __restrict__ x, const float* __restrict__ Wq,
    const float* __restrict__ Wk, const float* __restrict__ Wv,
    _Float16* __restrict__ xh, _Float16* __restrict__ Wh) {
  int i = blockIdx.x * 256 + threadIdx.x;
  if (i < N_TOK * OUTC / 4) {
    float4 f = ((const float4*)x)[i];
    half4 h; h[0] = (_Float16)f.x; h[1] = (_Float16)f.y; h[2] = (_Float16)f.z; h[3] = (_Float16)f.w;
    ((half4*)xh)[i] = h;
  }
  if (i < OUTC * OUTC / 4) {
    float4 a = ((const float4*)Wq)[i];
    float4 b = ((const float4*)Wk)[i];
    float4 c = ((const float4*)Wv)[i];
    half4 ha, hb, hc;
    ha[0]=(_Float16)a.x; ha[1]=(_Float16)a.y; ha[2]=(_Float16)a.z; ha[3]=(_Float16)a.w;
    hb[0]=(_Float16)b.x; hb[1]=(_Float16)b.y; hb[2]=(_Float16)b.z; hb[3]=(_Float16)b.w;
    hc[0]=(_Float16)c.x; hc[1]=(_Float16)c.y; hc[2]=(_Float16)c.z; hc[3]=(_Float16)c.w;
    ((half4*)Wh)[i] = ha;
    ((half4*)(Wh + OUTC*OUTC))[i] = hb;
    ((half4*)(Wh + 2*OUTC*OUTC))[i] = hc;
  }
}

// ---- kernel 2: QKV projection ----
// mat 0 -> Qh[hd][n][d] row-major, scaled by log2(e)/16 (exp2-domain softmax)
// mat 1 -> KF fragment-major: KF[hd*HSZ + ((t*4+c)*2+h)*512 + (g4*16+lr)*8 + ii]
//          = K[hd][t*64+16c+lr][32h+8*g4+ii]
// mat 2 -> VfT[o][n] f32 row-major
__global__ __launch_bounds__(256) void k_proj(
    const _Float16* __restrict__ xh, const _Float16* __restrict__ Wh,
    const float* __restrict__ bq, const float* __restrict__ bk,
    const float* __restrict__ bv,
    _Float16* __restrict__ Qh, _Float16* __restrict__ KF, float* __restrict__ VfT) {
  const int w = threadIdx.x >> 6, lane = threadIdx.x & 63;
  const int lr = lane & 15, lk = lane >> 4;
  const int n0 = blockIdx.x * 64 + w * 16;
  const int o0 = blockIdx.y * 64;
  const int mat = blockIdx.z;
  const _Float16* W = Wh + mat * (OUTC * OUTC);
  f32x4 acc[4] = {};
  const _Float16* xrow = xh + (n0 + lr) * OUTC + 8 * lk;
#pragma unroll
  for (int kk = 0; kk < 8; ++kk) {
    half8 a = *(const half8*)(xrow + 32 * kk);
#pragma unroll
    for (int c = 0; c < 4; ++c) {
      half8 b = *(const half8*)(W + (o0 + 16*c + lr) * OUTC + 32*kk + 8*lk);
      acc[c] = mfma16(a, b, acc[c]);
    }
  }
  const float* bias = (mat == 0) ? bq : (mat == 1) ? bk : bv;
  const int hd = blockIdx.y;   // head for mat 0/1
#pragma unroll
  for (int c = 0; c < 4; ++c) {
    int o = o0 + 16*c + lr;
    float bo = bias[o];
    if (mat == 2) {
      float4 vv;
      vv.x = acc[c][0] + bo; vv.y = acc[c][1] + bo;
      vv.z = acc[c][2] + bo; vv.w = acc[c][3] + bo;
      *(float4*)(VfT + (size_t)o * N_TOK + n0 + 4*lk) = vv;
    } else if (mat == 0) {
      int d = 16*c + lr;
      const float qs = 0.0625f * 1.4426950408889634f;   // (1/16) * log2(e)
#pragma unroll
      for (int r = 0; r < 4; ++r) {
        int n = n0 + 4*lk + r;
        Qh[((size_t)hd * N_TOK + n) * 64 + d] = (_Float16)((acc[c][r] + bo) * qs);
      }
    } else {
      int d = 16*c + lr;
      int h = d >> 5, g4K = (d >> 3) & 3, iiK = d & 7;
#pragma unroll
      for (int r = 0; r < 4; ++r) {
        int n = n0 + 4*lk + r;
        int tK = n >> 6, cK = (n >> 4) & 3, lrK = n & 15;
        KF[(size_t)hd * HSZ + ((tK*4 + cK)*2 + h)*512 + (g4K*16 + lrK)*8 + iiK] =
            (_Float16)(acc[c][r] + bo);
      }
    }
  }
}

// ---- kernel 3: smooth V over w-shifts, emit fragment-major + k-slot-permuted ----
// VF[vh*HSZ + t*4096 + f*8 + i]  (f = cc*128 + h*64 + g4*16 + lr)
//   = Vs[vh][16cc+lr][ t*64 + 32h + 16*(i>>2) + 4*g4 + (i&3) ]
__global__ __launch_bounds__(256) void k_smooth(
    const float* __restrict__ VfT, _Float16* __restrict__ VF) {
  const int t = blockIdx.x, vh = blockIdx.y;
  for (int f = threadIdx.x; f < 512; f += 256) {
    int cc = f >> 7, h = (f >> 6) & 1, g4 = (f >> 4) & 3, lr = f & 15;
    const float* src = VfT + (size_t)(vh*64 + 16*cc + lr) * N_TOK;
    int jbase = t*64 + 32*h + 4*g4;
    half8 out;
#pragma unroll
    for (int i = 0; i < 8; ++i) {
      int j = jbase + 16*(i >> 2) + (i & 3);
      float s = 0.f;
#pragma unroll
      for (int w = -4; w <= 4; w += 2) s += src[(j + w + N_TOK) % N_TOK];
      out[i] = (_Float16)s;
    }
    *(half8*)(VF + (size_t)vh * HSZ + (size_t)t * 4096 + f * 8) = out;
  }
}

// ---- kernel 4: flash attention, LDS-staged shared tiles, split-K x4 (global) ----
__global__ __launch_bounds__(256) void k_flash(
    const _Float16* __restrict__ Qh, const _Float16* __restrict__ KF,
    const _Float16* __restrict__ VF,
    _Float16* __restrict__ Opart, float* __restrict__ Lpart) {
  __shared__ __align__(16) _Float16 lds[2][8192];   // [buf][ K:0..4095 | V:4096..8191 ]
  const int wv = threadIdx.x >> 6, lane = threadIdx.x & 63;
  const int lr = lane & 15, g4 = lane >> 4;
  const int strip = blockIdx.x * 4 + wv;      // 0..143, 16 queries each
  const int n0 = strip * 16;
  const int pair = blockIdx.y;                // hd*4 + gk
  const int hd = pair >> 2, gk = pair & 3;
  const int chunk = blockIdx.z;               // 9 tiles each
  const int vh = (2*hd + 4 - gk) & 3;

  const _Float16* Qp = Qh + ((size_t)hd * N_TOK + n0 + lr) * 64 + 8*g4;
  const half8 q0 = *(const half8*)(Qp);
  const half8 q1 = *(const half8*)(Qp + 32);

  const _Float16* Kt = KF + (size_t)gk * HSZ + (size_t)chunk * 9 * 4096;
  const _Float16* Vt = VF + (size_t)vh * HSZ + (size_t)chunk * 9 * 4096;
  // wave wv stages one 4KB quarter of the 16KB tile-pair (lane-linear layout)
  const _Float16* gsrc = (wv < 2 ? Kt : Vt) + (wv & 1) * 2048 + lane * 8;
  const int ldsoff = (wv < 2 ? 0 : 4096) + (wv & 1) * 2048;

  f32x4 acc[4] = {};   // acc[cc][r] = out[n0+lr][16*cc + 4*g4 + r] (unnormalized)
  f32x4 accl = {};     // ones-row MFMA: accl[*] = full softmax denom for query lr
  half8 ones;
#pragma unroll
  for (int i = 0; i < 8; ++i) ones[i] = (_Float16)1.0f;

  auto stage = [&](int t, int b) {
    const _Float16* s = gsrc + (size_t)t * 4096;
    _Float16* d = &lds[b][ldsoff];
    gload_lds16(s,        d);
    gload_lds16(s + 512,  d + 512);
    gload_lds16(s + 1024, d + 1024);
    gload_lds16(s + 1536, d + 1536);
  };
  auto body = [&](int b) {
    const _Float16* ldsK = &lds[b][0]    + lane * 8;
    const _Float16* ldsV = &lds[b][4096] + lane * 8;
    f32x4 s[4];
    __builtin_amdgcn_s_setprio(1);
#pragma unroll
    for (int c = 0; c < 4; ++c) {
      f32x4 t = {};
      t = mfma16(*(const half8*)(ldsK + c*1024),       q0, t);
      t = mfma16(*(const half8*)(ldsK + c*1024 + 512), q1, t);
      s[c] = t;  // s[c][r] = S[key 16c+4*g4+r][query lr], log2-domain
    }
    __builtin_amdgcn_s_setprio(0);
    float p[16];
#pragma unroll
    for (int c = 0; c < 4; ++c)
#pragma unroll
      for (int r = 0; r < 4; ++r) p[4*c + r] = exp2f(s[c][r]);
    half8 pb0, pb1;
#pragma unroll
    for (int ii = 0; ii < 8; ++ii) { pb0[ii] = (_Float16)p[ii]; pb1[ii] = (_Float16)p[8 + ii]; }
    __builtin_amdgcn_s_setprio(1);
#pragma unroll
    for (int cc = 0; cc < 4; ++cc) {
      acc[cc] = mfma16(*(const half8*)(ldsV + cc*1024),       pb0, acc[cc]);
      acc[cc] = mfma16(*(const half8*)(ldsV + cc*1024 + 512), pb1, acc[cc]);
    }
    accl = mfma16(ones, pb0, accl);   // sums P over ALL 32 k-slots (all lane groups)
    accl = mfma16(ones, pb1, accl);
    __builtin_amdgcn_s_setprio(0);
  };

  stage(0, 0);
  __syncthreads();                      // syncthreads drains vmcnt before barrier
#pragma unroll 1
  for (int t = 0; t < 9; ++t) {
    if (t < 8) stage(t + 1, (t + 1) & 1);
    body(t & 1);
    __syncthreads();                    // protects buf[t&1] from next stage + drains
  }

  // epilogue: accl[0] is the full per-query denom (identical across r and g4)
  float inv = 1.0f / accl[0];
  _Float16* Od = Opart + (((size_t)chunk * 16 + pair) * N_TOK + n0 + lr) * 64;
#pragma unroll
  for (int cc = 0; cc < 4; ++cc) {
    half4 h;
#pragma unroll
    for (int r = 0; r < 4; ++r) h[r] = (_Float16)(acc[cc][r] * inv);
    *(half4*)(Od + 16*cc + 4*g4) = h;
  }
  if (g4 == 0)
    Lpart[((size_t)chunk * 16 + pair) * N_TOK + n0 + lr] = accl[0];
}

// ---- kernel 5: merge split-K chunks (l-weighted), weight by c_g, sum over gk ----
__global__ __launch_bounds__(256) void k_combine(
    const _Float16* __restrict__ Opart, const float* __restrict__ Lpart,
    float* __restrict__ out) {
  int gid = blockIdx.x * 256 + threadIdx.x;   // 73728 total
  int hd = gid / (N_TOK * 8);
  int rem = gid % (N_TOK * 8);
  int n = rem >> 3, db = (rem & 7) * 8;
  float acc[8] = {};
#pragma unroll
  for (int gk = 0; gk < 4; ++gk) {
    float cg = (((hd - gk) & 3) == 2) ? 2.0f : 1.0f;
    int pair = hd * 4 + gk;
    float la[4], lsum = 0.f;
#pragma unroll
    for (int ch = 0; ch < 4; ++ch) {
      la[ch] = Lpart[((size_t)ch * 16 + pair) * N_TOK + n];
      lsum += la[ch];
    }
    float rs = cg / lsum;
#pragma unroll
    for (int ch = 0; ch < 4; ++ch) {
      half8 v = *(const half8*)(Opart + (((size_t)ch * 16 + pair) * N_TOK + n) * 64 + db);
      float w = la[ch] * rs;
#pragma unroll
      for (int i = 0; i < 8; ++i) acc[i] += w * (float)v[i];
    }
  }
  float* dst = out + (size_t)n * OUTC + hd * 64 + db;
  float4 r0, r1;
  r0.x = acc[0]; r0.y = acc[1]; r0.z = acc[2]; r0.w = acc[3];
  r1.x = acc[4]; r1.y = acc[5]; r1.z = acc[6]; r1.w = acc[7];
  *(float4*)(dst)     = r0;
  *(float4*)(dst + 4) = r1;
}

extern "C" void kernel_launch(void* const* d_in, const int* in_sizes, int n_in,
                              void* d_out, int out_size, void* d_ws, size_t ws_size,
                              hipStream_t stream) {
  (void)in_sizes; (void)n_in; (void)out_size; (void)ws_size;
  const float* x  = (const float*)d_in[0];
  const float* Wq = (const float*)d_in[1];
  const float* bq = (const float*)d_in[2];
  const float* Wk = (const float*)d_in[3];
  const float* bk = (const float*)d_in[4];
  const float* Wv = (const float*)d_in[5];
  const float* bv = (const float*)d_in[6];

  char* ws = (char*)d_ws;
  _Float16* xh  = (_Float16*)(ws);              // 1,179,648 B (dead after k_proj)
  float*    Lp  = (float*)   (ws);              // reuses xh region (589,824 B)
  _Float16* Wh  = (_Float16*)(ws + 1179648);    //   393,216 B
  _Float16* Qh  = (_Float16*)(ws + 1572864);    // 1,179,648 B
  _Float16* KF  = (_Float16*)(ws + 2752512);    // 1,179,648 B (fragment-major)
  float*    VfT = (float*)   (ws + 3932160);    // 2,359,296 B
  _Float16* VF  = (_Float16*)(ws + 6291456);    // 1,179,648 B (fragment-major)
  _Float16* Op  = (_Float16*)(ws + 7471104);    // 9,437,184 B (ends 16,908,288)
  float* out = (float*)d_out;

  k_convert<<<dim3(576), dim3(256), 0, stream>>>(x, Wq, Wk, Wv, xh, Wh);
  k_proj   <<<dim3(36, 4, 3), dim3(256), 0, stream>>>(xh, Wh, bq, bk, bv, Qh, KF, VfT);
  k_smooth <<<dim3(36, 4), dim3(256), 0, stream>>>(VfT, VF);
  k_flash  <<<dim3(36, 16, 4), dim3(256), 0, stream>>>(Qh, KF, VF, Op, Lp);
  k_combine<<<dim3(288), dim3(256), 0, stream>>>(Op, Lp, out);
}

// Round 9
// 67.455 us; speedup vs baseline: 6.3715x; 1.0966x over previous
//
#include <hip/hip_runtime.h>

// SparseSelfAttention, algebraically reduced:
//   out[hd] = sum_g c_g * softmax(Q_hd K_g^T / 16) @ Vs[(2hd-g)%4]
//   Vs[head][j] = sum_{w=-2..2} v[head][(j+2w)%N]
//   c_g = 2 if (hd-g)%4==2 else 1
// N=2304 tokens, 4 heads, dh=64.
//
// k_flash v4: LDS-staged shared K/V tiles (global_load_lds w16, dbuf, one
// barrier/tile), 2 query-strips per wave (each ds_read feeds 2 strips),
// raw v_exp_f32 via __builtin_amdgcn_exp2f (Q pre-scaled by log2e/16),
// packed f32->f16 via cvt_pkrtz, softmax denom via ones-row MFMA.
// R5 lesson: no waves-per-EU clamp. R6 lesson: keep VGPR < 128.
// R8 lesson: cvt_pkrtz returns __fp16-based vec2 -- union must use that type.

#define N_TOK 2304
#define OUTC 256
#define HSZ (N_TOK * 64)   // halfs per head = 147456

typedef _Float16 half8 __attribute__((ext_vector_type(8)));
typedef _Float16 half4 __attribute__((ext_vector_type(4)));
typedef __fp16 fp16x2 __attribute__((ext_vector_type(2)));
typedef float f32x4 __attribute__((ext_vector_type(4)));

typedef __attribute__((address_space(3))) unsigned int as3_u32;
typedef __attribute__((address_space(1))) unsigned int as1_u32;

__device__ __forceinline__ f32x4 mfma16(half8 a, half8 b, f32x4 c) {
  return __builtin_amdgcn_mfma_f32_16x16x32_f16(a, b, c, 0, 0, 0);
}

__device__ __forceinline__ void gload_lds16(const _Float16* g, _Float16* l) {
  __builtin_amdgcn_global_load_lds((const as1_u32*)g, (as3_u32*)l, 16, 0, 0);
}

union H8U { half8 h8; fp16x2 h2[4]; };

// ---- kernel 1: fp32 -> fp16 conversion (vectorized x4) ----
__global__ __launch_bounds__(256) void k_convert(
    const float* __restrict__ x, const float* __restrict__ Wq,
    const float* __restrict__ Wk, const float* __restrict__ Wv,
    _Float16* __restrict__ xh, _Float16* __restrict__ Wh) {
  int i = blockIdx.x * 256 + threadIdx.x;
  if (i < N_TOK * OUTC / 4) {
    float4 f = ((const float4*)x)[i];
    half4 h; h[0] = (_Float16)f.x; h[1] = (_Float16)f.y; h[2] = (_Float16)f.z; h[3] = (_Float16)f.w;
    ((half4*)xh)[i] = h;
  }
  if (i < OUTC * OUTC / 4) {
    float4 a = ((const float4*)Wq)[i];
    float4 b = ((const float4*)Wk)[i];
    float4 c = ((const float4*)Wv)[i];
    half4 ha, hb, hc;
    ha[0]=(_Float16)a.x; ha[1]=(_Float16)a.y; ha[2]=(_Float16)a.z; ha[3]=(_Float16)a.w;
    hb[0]=(_Float16)b.x; hb[1]=(_Float16)b.y; hb[2]=(_Float16)b.z; hb[3]=(_Float16)b.w;
    hc[0]=(_Float16)c.x; hc[1]=(_Float16)c.y; hc[2]=(_Float16)c.z; hc[3]=(_Float16)c.w;
    ((half4*)Wh)[i] = ha;
    ((half4*)(Wh + OUTC*OUTC))[i] = hb;
    ((half4*)(Wh + 2*OUTC*OUTC))[i] = hc;
  }
}

// ---- kernel 2: QKV projection ----
// mat 0 -> Qh[hd][n][d] row-major, scaled by log2(e)/16 (exp2-domain softmax)
// mat 1 -> KF fragment-major: KF[hd*HSZ + ((t*4+c)*2+h)*512 + (g4*16+lr)*8 + ii]
//          = K[hd][t*64+16c+lr][32h+8*g4+ii]
// mat 2 -> VfT[o][n] f32 row-major
__global__ __launch_bounds__(256) void k_proj(
    const _Float16* __restrict__ xh, const _Float16* __restrict__ Wh,
    const float* __restrict__ bq, const float* __restrict__ bk,
    const float* __restrict__ bv,
    _Float16* __restrict__ Qh, _Float16* __restrict__ KF, float* __restrict__ VfT) {
  const int w = threadIdx.x >> 6, lane = threadIdx.x & 63;
  const int lr = lane & 15, lk = lane >> 4;
  const int n0 = blockIdx.x * 64 + w * 16;
  const int o0 = blockIdx.y * 64;
  const int mat = blockIdx.z;
  const _Float16* W = Wh + mat * (OUTC * OUTC);
  f32x4 acc[4] = {};
  const _Float16* xrow = xh + (n0 + lr) * OUTC + 8 * lk;
#pragma unroll
  for (int kk = 0; kk < 8; ++kk) {
    half8 a = *(const half8*)(xrow + 32 * kk);
#pragma unroll
    for (int c = 0; c < 4; ++c) {
      half8 b = *(const half8*)(W + (o0 + 16*c + lr) * OUTC + 32*kk + 8*lk);
      acc[c] = mfma16(a, b, acc[c]);
    }
  }
  const float* bias = (mat == 0) ? bq : (mat == 1) ? bk : bv;
  const int hd = blockIdx.y;   // head for mat 0/1
#pragma unroll
  for (int c = 0; c < 4; ++c) {
    int o = o0 + 16*c + lr;
    float bo = bias[o];
    if (mat == 2) {
      float4 vv;
      vv.x = acc[c][0] + bo; vv.y = acc[c][1] + bo;
      vv.z = acc[c][2] + bo; vv.w = acc[c][3] + bo;
      *(float4*)(VfT + (size_t)o * N_TOK + n0 + 4*lk) = vv;
    } else if (mat == 0) {
      int d = 16*c + lr;
      const float qs = 0.0625f * 1.4426950408889634f;   // (1/16) * log2(e)
#pragma unroll
      for (int r = 0; r < 4; ++r) {
        int n = n0 + 4*lk + r;
        Qh[((size_t)hd * N_TOK + n) * 64 + d] = (_Float16)((acc[c][r] + bo) * qs);
      }
    } else {
      int d = 16*c + lr;
      int h = d >> 5, g4K = (d >> 3) & 3, iiK = d & 7;
#pragma unroll
      for (int r = 0; r < 4; ++r) {
        int n = n0 + 4*lk + r;
        int tK = n >> 6, cK = (n >> 4) & 3, lrK = n & 15;
        KF[(size_t)hd * HSZ + ((tK*4 + cK)*2 + h)*512 + (g4K*16 + lrK)*8 + iiK] =
            (_Float16)(acc[c][r] + bo);
      }
    }
  }
}

// ---- kernel 3: smooth V over w-shifts, emit fragment-major + k-slot-permuted ----
// VF[vh*HSZ + t*4096 + f*8 + i]  (f = cc*128 + h*64 + g4*16 + lr)
//   = Vs[vh][16cc+lr][ t*64 + 32h + 16*(i>>2) + 4*g4 + (i&3) ]
__global__ __launch_bounds__(256) void k_smooth(
    const float* __restrict__ VfT, _Float16* __restrict__ VF) {
  const int t = blockIdx.x, vh = blockIdx.y;
  for (int f = threadIdx.x; f < 512; f += 256) {
    int cc = f >> 7, h = (f >> 6) & 1, g4 = (f >> 4) & 3, lr = f & 15;
    const float* src = VfT + (size_t)(vh*64 + 16*cc + lr) * N_TOK;
    int jbase = t*64 + 32*h + 4*g4;
    half8 out;
#pragma unroll
    for (int i = 0; i < 8; ++i) {
      int j = jbase + 16*(i >> 2) + (i & 3);
      float s = 0.f;
#pragma unroll
      for (int w = -4; w <= 4; w += 2) s += src[(j + w + N_TOK) % N_TOK];
      out[i] = (_Float16)s;
    }
    *(half8*)(VF + (size_t)vh * HSZ + (size_t)t * 4096 + f * 8) = out;
  }
}

// ---- kernel 4: flash attention, LDS tiles shared by 4 waves x 2 strips ----
__global__ __launch_bounds__(256) void k_flash(
    const _Float16* __restrict__ Qh, const _Float16* __restrict__ KF,
    const _Float16* __restrict__ VF,
    _Float16* __restrict__ Opart, float* __restrict__ Lpart) {
  __shared__ __align__(16) _Float16 lds[2][8192];   // [buf][ K:0..4095 | V:4096..8191 ]
  const int wv = threadIdx.x >> 6, lane = threadIdx.x & 63;
  const int lr = lane & 15, g4 = lane >> 4;
  const int strip = blockIdx.x * 4 + wv;      // 0..71, 32 queries each
  const int n0 = strip * 32;
  const int pair = blockIdx.y;                // hd*4 + gk
  const int hd = pair >> 2, gk = pair & 3;
  const int chunk = blockIdx.z;               // 9 tiles each
  const int vh = (2*hd + 4 - gk) & 3;

  const _Float16* Qp = Qh + ((size_t)hd * N_TOK + n0 + lr) * 64 + 8*g4;
  const half8 qa0 = *(const half8*)(Qp);
  const half8 qa1 = *(const half8*)(Qp + 32);
  const half8 qb0 = *(const half8*)(Qp + 16*64);
  const half8 qb1 = *(const half8*)(Qp + 16*64 + 32);

  const _Float16* Kt = KF + (size_t)gk * HSZ + (size_t)chunk * 9 * 4096;
  const _Float16* Vt = VF + (size_t)vh * HSZ + (size_t)chunk * 9 * 4096;
  // wave wv stages one 4KB quarter of the 16KB tile-pair (lane-linear layout)
  const _Float16* gsrc = (wv < 2 ? Kt : Vt) + (wv & 1) * 2048 + lane * 8;
  const int ldsoff = (wv < 2 ? 0 : 4096) + (wv & 1) * 2048;

  f32x4 accA[4] = {}, accB[4] = {};
  f32x4 acclA = {}, acclB = {};
  half8 ones;
#pragma unroll
  for (int i = 0; i < 8; ++i) ones[i] = (_Float16)1.0f;

  auto stage = [&](int t, int b) {
    const _Float16* s = gsrc + (size_t)t * 4096;
    _Float16* d = &lds[b][ldsoff];
    gload_lds16(s,        d);
    gload_lds16(s + 512,  d + 512);
    gload_lds16(s + 1024, d + 1024);
    gload_lds16(s + 1536, d + 1536);
  };
  auto body = [&](int b) {
    const _Float16* ldsK = &lds[b][0]    + lane * 8;
    const _Float16* ldsV = &lds[b][4096] + lane * 8;
    f32x4 sA[4], sB[4];
    __builtin_amdgcn_s_setprio(1);
#pragma unroll
    for (int c = 0; c < 4; ++c) {
      half8 k0 = *(const half8*)(ldsK + c*1024);
      half8 k1 = *(const half8*)(ldsK + c*1024 + 512);
      f32x4 tA = {}; tA = mfma16(k0, qa0, tA); tA = mfma16(k1, qa1, tA); sA[c] = tA;
      f32x4 tB = {}; tB = mfma16(k0, qb0, tB); tB = mfma16(k1, qb1, tB); sB[c] = tB;
    }
    __builtin_amdgcn_s_setprio(0);
    // raw v_exp_f32 (log2-domain, |s| small -> no clamp needed) + packed cvt
    H8U a0, a1, b0, b1;
#pragma unroll
    for (int c = 0; c < 4; ++c) {
      float eA0 = __builtin_amdgcn_exp2f(sA[c][0]);
      float eA1 = __builtin_amdgcn_exp2f(sA[c][1]);
      float eA2 = __builtin_amdgcn_exp2f(sA[c][2]);
      float eA3 = __builtin_amdgcn_exp2f(sA[c][3]);
      float eB0 = __builtin_amdgcn_exp2f(sB[c][0]);
      float eB1 = __builtin_amdgcn_exp2f(sB[c][1]);
      float eB2 = __builtin_amdgcn_exp2f(sB[c][2]);
      float eB3 = __builtin_amdgcn_exp2f(sB[c][3]);
      H8U* da = (c < 2) ? &a0 : &a1;
      H8U* db = (c < 2) ? &b0 : &b1;
      int base = (c & 1) * 2;
      da->h2[base]     = __builtin_amdgcn_cvt_pkrtz(eA0, eA1);
      da->h2[base + 1] = __builtin_amdgcn_cvt_pkrtz(eA2, eA3);
      db->h2[base]     = __builtin_amdgcn_cvt_pkrtz(eB0, eB1);
      db->h2[base + 1] = __builtin_amdgcn_cvt_pkrtz(eB2, eB3);
    }
    __builtin_amdgcn_s_setprio(1);
#pragma unroll
    for (int cc = 0; cc < 4; ++cc) {
      half8 v0 = *(const half8*)(ldsV + cc*1024);
      half8 v1 = *(const half8*)(ldsV + cc*1024 + 512);
      accA[cc] = mfma16(v0, a0.h8, accA[cc]); accA[cc] = mfma16(v1, a1.h8, accA[cc]);
      accB[cc] = mfma16(v0, b0.h8, accB[cc]); accB[cc] = mfma16(v1, b1.h8, accB[cc]);
    }
    acclA = mfma16(ones, a0.h8, acclA); acclA = mfma16(ones, a1.h8, acclA);
    acclB = mfma16(ones, b0.h8, acclB); acclB = mfma16(ones, b1.h8, acclB);
    __builtin_amdgcn_s_setprio(0);
  };

  stage(0, 0);
  __syncthreads();
#pragma unroll 1
  for (int t = 0; t < 9; ++t) {
    if (t < 8) stage(t + 1, (t + 1) & 1);
    body(t & 1);
    __syncthreads();                    // protects buf[t&1] from next stage + drains
  }

  // epilogue: accl[0] is the full per-query denom (identical across r and g4)
  float invA = 1.0f / acclA[0];
  float invB = 1.0f / acclB[0];
  _Float16* Oa = Opart + (((size_t)chunk * 16 + pair) * N_TOK + n0 + lr) * 64;
  _Float16* Ob = Oa + 16 * 64;
#pragma unroll
  for (int cc = 0; cc < 4; ++cc) {
    half4 ha, hb;
#pragma unroll
    for (int r = 0; r < 4; ++r) {
      ha[r] = (_Float16)(accA[cc][r] * invA);
      hb[r] = (_Float16)(accB[cc][r] * invB);
    }
    *(half4*)(Oa + 16*cc + 4*g4) = ha;
    *(half4*)(Ob + 16*cc + 4*g4) = hb;
  }
  if (g4 == 0) {
    Lpart[((size_t)chunk * 16 + pair) * N_TOK + n0 + lr] = acclA[0];
    Lpart[((size_t)chunk * 16 + pair) * N_TOK + n0 + 16 + lr] = acclB[0];
  }
}

// ---- kernel 5: merge split-K chunks (l-weighted), weight by c_g, sum over gk ----
__global__ __launch_bounds__(256) void k_combine(
    const _Float16* __restrict__ Opart, const float* __restrict__ Lpart,
    float* __restrict__ out) {
  int gid = blockIdx.x * 256 + threadIdx.x;   // 73728 total
  int hd = gid / (N_TOK * 8);
  int rem = gid % (N_TOK * 8);
  int n = rem >> 3, db = (rem & 7) * 8;
  float acc[8] = {};
#pragma unroll
  for (int gk = 0; gk < 4; ++gk) {
    float cg = (((hd - gk) & 3) == 2) ? 2.0f : 1.0f;
    int pair = hd * 4 + gk;
    float la[4], lsum = 0.f;
#pragma unroll
    for (int ch = 0; ch < 4; ++ch) {
      la[ch] = Lpart[((size_t)ch * 16 + pair) * N_TOK + n];
      lsum += la[ch];
    }
    float rs = cg / lsum;
#pragma unroll
    for (int ch = 0; ch < 4; ++ch) {
      half8 v = *(const half8*)(Opart + (((size_t)ch * 16 + pair) * N_TOK + n) * 64 + db);
      float w = la[ch] * rs;
#pragma unroll
      for (int i = 0; i < 8; ++i) acc[i] += w * (float)v[i];
    }
  }
  float* dst = out + (size_t)n * OUTC + hd * 64 + db;
  float4 r0, r1;
  r0.x = acc[0]; r0.y = acc[1]; r0.z = acc[2]; r0.w = acc[3];
  r1.x = acc[4]; r1.y = acc[5]; r1.z = acc[6]; r1.w = acc[7];
  *(float4*)(dst)     = r0;
  *(float4*)(dst + 4) = r1;
}

extern "C" void kernel_launch(void* const* d_in, const int* in_sizes, int n_in,
                              void* d_out, int out_size, void* d_ws, size_t ws_size,
                              hipStream_t stream) {
  (void)in_sizes; (void)n_in; (void)out_size; (void)ws_size;
  const float* x  = (const float*)d_in[0];
  const float* Wq = (const float*)d_in[1];
  const float* bq = (const float*)d_in[2];
  const float* Wk = (const float*)d_in[3];
  const float* bk = (const float*)d_in[4];
  const float* Wv = (const float*)d_in[5];
  const float* bv = (const float*)d_in[6];

  char* ws = (char*)d_ws;
  _Float16* xh  = (_Float16*)(ws);              // 1,179,648 B (dead after k_proj)
  float*    Lp  = (float*)   (ws);              // reuses xh region (589,824 B)
  _Float16* Wh  = (_Float16*)(ws + 1179648);    //   393,216 B
  _Float16* Qh  = (_Float16*)(ws + 1572864);    // 1,179,648 B
  _Float16* KF  = (_Float16*)(ws + 2752512);    // 1,179,648 B (fragment-major)
  float*    VfT = (float*)   (ws + 3932160);    // 2,359,296 B
  _Float16* VF  = (_Float16*)(ws + 6291456);    // 1,179,648 B (fragment-major)
  _Float16* Op  = (_Float16*)(ws + 7471104);    // 9,437,184 B (ends 16,908,288)
  float* out = (float*)d_out;

  k_convert<<<dim3(576), dim3(256), 0, stream>>>(x, Wq, Wk, Wv, xh, Wh);
  k_proj   <<<dim3(36, 4, 3), dim3(256), 0, stream>>>(xh, Wh, bq, bk, bv, Qh, KF, VfT);
  k_smooth <<<dim3(36, 4), dim3(256), 0, stream>>>(VfT, VF);
  k_flash  <<<dim3(18, 16, 4), dim3(256), 0, stream>>>(Qh, KF, VF, Op, Lp);
  k_combine<<<dim3(288), dim3(256), 0, stream>>>(Op, Lp, out);
}

// Round 10
// 67.328 us; speedup vs baseline: 6.3835x; 1.0019x over previous
//
#include <hip/hip_runtime.h>

// SparseSelfAttention, algebraically reduced:
//   out[hd] = sum_g c_g * softmax(Q_hd K_g^T / 16) @ Vs[(2hd-g)%4]
//   Vs[head][j] = sum_{w=-2..2} v[head][(j+2w)%N]
//   c_g = 2 if (hd-g)%4==2 else 1
// N=2304 tokens, 4 heads, dh=64.
//
// k_flash v5: LDS-staged shared K/V tiles (global_load_lds w16, dbuf),
// counted-vmcnt pipeline (T4): per tile, each wave waits vmcnt(4) (own
// current-tile loads done, next-tile prefetch stays IN FLIGHT across the
// barrier) + raw s_barrier -- no vmcnt(0) drain in the main loop (that drain
// was the R7/R9 stall). 2 query-strips per wave, raw v_exp2, cvt_pkrtz,
// ones-row-MFMA softmax denom.
// R5 lesson: no waves-per-EU clamp. R6: VGPR < 128. R8: cvt_pkrtz is __fp16.

#define N_TOK 2304
#define OUTC 256
#define HSZ (N_TOK * 64)   // halfs per head = 147456

typedef _Float16 half8 __attribute__((ext_vector_type(8)));
typedef _Float16 half4 __attribute__((ext_vector_type(4)));
typedef __fp16 fp16x2 __attribute__((ext_vector_type(2)));
typedef float f32x4 __attribute__((ext_vector_type(4)));

typedef __attribute__((address_space(3))) unsigned int as3_u32;
typedef __attribute__((address_space(1))) unsigned int as1_u32;

__device__ __forceinline__ f32x4 mfma16(half8 a, half8 b, f32x4 c) {
  return __builtin_amdgcn_mfma_f32_16x16x32_f16(a, b, c, 0, 0, 0);
}

__device__ __forceinline__ void gload_lds16(const _Float16* g, _Float16* l) {
  __builtin_amdgcn_global_load_lds((const as1_u32*)g, (as3_u32*)l, 16, 0, 0);
}

union H8U { half8 h8; fp16x2 h2[4]; };

// ---- kernel 1: fp32 -> fp16 conversion (vectorized x4) ----
__global__ __launch_bounds__(256) void k_convert(
    const float* __restrict__ x, const float* __restrict__ Wq,
    const float* __restrict__ Wk, const float* __restrict__ Wv,
    _Float16* __restrict__ xh, _Float16* __restrict__ Wh) {
  int i = blockIdx.x * 256 + threadIdx.x;
  if (i < N_TOK * OUTC / 4) {
    float4 f = ((const float4*)x)[i];
    half4 h; h[0] = (_Float16)f.x; h[1] = (_Float16)f.y; h[2] = (_Float16)f.z; h[3] = (_Float16)f.w;
    ((half4*)xh)[i] = h;
  }
  if (i < OUTC * OUTC / 4) {
    float4 a = ((const float4*)Wq)[i];
    float4 b = ((const float4*)Wk)[i];
    float4 c = ((const float4*)Wv)[i];
    half4 ha, hb, hc;
    ha[0]=(_Float16)a.x; ha[1]=(_Float16)a.y; ha[2]=(_Float16)a.z; ha[3]=(_Float16)a.w;
    hb[0]=(_Float16)b.x; hb[1]=(_Float16)b.y; hb[2]=(_Float16)b.z; hb[3]=(_Float16)b.w;
    hc[0]=(_Float16)c.x; hc[1]=(_Float16)c.y; hc[2]=(_Float16)c.z; hc[3]=(_Float16)c.w;
    ((half4*)Wh)[i] = ha;
    ((half4*)(Wh + OUTC*OUTC))[i] = hb;
    ((half4*)(Wh + 2*OUTC*OUTC))[i] = hc;
  }
}

// ---- kernel 2: QKV projection ----
// mat 0 -> Qh[hd][n][d] row-major, scaled by log2(e)/16 (exp2-domain softmax)
// mat 1 -> KF fragment-major: KF[hd*HSZ + ((t*4+c)*2+h)*512 + (g4*16+lr)*8 + ii]
//          = K[hd][t*64+16c+lr][32h+8*g4+ii]
// mat 2 -> VfT[o][n] f32 row-major
__global__ __launch_bounds__(256) void k_proj(
    const _Float16* __restrict__ xh, const _Float16* __restrict__ Wh,
    const float* __restrict__ bq, const float* __restrict__ bk,
    const float* __restrict__ bv,
    _Float16* __restrict__ Qh, _Float16* __restrict__ KF, float* __restrict__ VfT) {
  const int w = threadIdx.x >> 6, lane = threadIdx.x & 63;
  const int lr = lane & 15, lk = lane >> 4;
  const int n0 = blockIdx.x * 64 + w * 16;
  const int o0 = blockIdx.y * 64;
  const int mat = blockIdx.z;
  const _Float16* W = Wh + mat * (OUTC * OUTC);
  f32x4 acc[4] = {};
  const _Float16* xrow = xh + (n0 + lr) * OUTC + 8 * lk;
#pragma unroll
  for (int kk = 0; kk < 8; ++kk) {
    half8 a = *(const half8*)(xrow + 32 * kk);
#pragma unroll
    for (int c = 0; c < 4; ++c) {
      half8 b = *(const half8*)(W + (o0 + 16*c + lr) * OUTC + 32*kk + 8*lk);
      acc[c] = mfma16(a, b, acc[c]);
    }
  }
  const float* bias = (mat == 0) ? bq : (mat == 1) ? bk : bv;
  const int hd = blockIdx.y;   // head for mat 0/1
#pragma unroll
  for (int c = 0; c < 4; ++c) {
    int o = o0 + 16*c + lr;
    float bo = bias[o];
    if (mat == 2) {
      float4 vv;
      vv.x = acc[c][0] + bo; vv.y = acc[c][1] + bo;
      vv.z = acc[c][2] + bo; vv.w = acc[c][3] + bo;
      *(float4*)(VfT + (size_t)o * N_TOK + n0 + 4*lk) = vv;
    } else if (mat == 0) {
      int d = 16*c + lr;
      const float qs = 0.0625f * 1.4426950408889634f;   // (1/16) * log2(e)
#pragma unroll
      for (int r = 0; r < 4; ++r) {
        int n = n0 + 4*lk + r;
        Qh[((size_t)hd * N_TOK + n) * 64 + d] = (_Float16)((acc[c][r] + bo) * qs);
      }
    } else {
      int d = 16*c + lr;
      int h = d >> 5, g4K = (d >> 3) & 3, iiK = d & 7;
#pragma unroll
      for (int r = 0; r < 4; ++r) {
        int n = n0 + 4*lk + r;
        int tK = n >> 6, cK = (n >> 4) & 3, lrK = n & 15;
        KF[(size_t)hd * HSZ + ((tK*4 + cK)*2 + h)*512 + (g4K*16 + lrK)*8 + iiK] =
            (_Float16)(acc[c][r] + bo);
      }
    }
  }
}

// ---- kernel 3: smooth V over w-shifts, emit fragment-major + k-slot-permuted ----
// VF[vh*HSZ + t*4096 + f*8 + i]  (f = cc*128 + h*64 + g4*16 + lr)
//   = Vs[vh][16cc+lr][ t*64 + 32h + 16*(i>>2) + 4*g4 + (i&3) ]
__global__ __launch_bounds__(256) void k_smooth(
    const float* __restrict__ VfT, _Float16* __restrict__ VF) {
  const int t = blockIdx.x, vh = blockIdx.y;
  for (int f = threadIdx.x; f < 512; f += 256) {
    int cc = f >> 7, h = (f >> 6) & 1, g4 = (f >> 4) & 3, lr = f & 15;
    const float* src = VfT + (size_t)(vh*64 + 16*cc + lr) * N_TOK;
    int jbase = t*64 + 32*h + 4*g4;
    half8 out;
#pragma unroll
    for (int i = 0; i < 8; ++i) {
      int j = jbase + 16*(i >> 2) + (i & 3);
      float s = 0.f;
#pragma unroll
      for (int w = -4; w <= 4; w += 2) s += src[(j + w + N_TOK) % N_TOK];
      out[i] = (_Float16)s;
    }
    *(half8*)(VF + (size_t)vh * HSZ + (size_t)t * 4096 + f * 8) = out;
  }
}

// ---- kernel 4: flash attention, LDS tiles, counted-vmcnt pipeline ----
__global__ __launch_bounds__(256) void k_flash(
    const _Float16* __restrict__ Qh, const _Float16* __restrict__ KF,
    const _Float16* __restrict__ VF,
    _Float16* __restrict__ Opart, float* __restrict__ Lpart) {
  __shared__ __align__(16) _Float16 lds[2][8192];   // [buf][ K:0..4095 | V:4096..8191 ]
  const int wv = threadIdx.x >> 6, lane = threadIdx.x & 63;
  const int lr = lane & 15, g4 = lane >> 4;
  const int strip = blockIdx.x * 4 + wv;      // 0..71, 32 queries each
  const int n0 = strip * 32;
  const int pair = blockIdx.y;                // hd*4 + gk
  const int hd = pair >> 2, gk = pair & 3;
  const int chunk = blockIdx.z;               // 9 tiles each
  const int vh = (2*hd + 4 - gk) & 3;

  const _Float16* Qp = Qh + ((size_t)hd * N_TOK + n0 + lr) * 64 + 8*g4;
  const half8 qa0 = *(const half8*)(Qp);
  const half8 qa1 = *(const half8*)(Qp + 32);
  const half8 qb0 = *(const half8*)(Qp + 16*64);
  const half8 qb1 = *(const half8*)(Qp + 16*64 + 32);

  const _Float16* Kt = KF + (size_t)gk * HSZ + (size_t)chunk * 9 * 4096;
  const _Float16* Vt = VF + (size_t)vh * HSZ + (size_t)chunk * 9 * 4096;
  // wave wv stages one 4KB quarter of the 16KB tile-pair (lane-linear layout)
  const _Float16* gsrc = (wv < 2 ? Kt : Vt) + (wv & 1) * 2048 + lane * 8;
  const int ldsoff = (wv < 2 ? 0 : 4096) + (wv & 1) * 2048;

  f32x4 accA[4] = {}, accB[4] = {};
  f32x4 acclA = {}, acclB = {};
  half8 ones;
#pragma unroll
  for (int i = 0; i < 8; ++i) ones[i] = (_Float16)1.0f;

  auto stage = [&](int t, int b) {
    const _Float16* s = gsrc + (size_t)t * 4096;
    _Float16* d = &lds[b][ldsoff];
    gload_lds16(s,        d);
    gload_lds16(s + 512,  d + 512);
    gload_lds16(s + 1024, d + 1024);
    gload_lds16(s + 1536, d + 1536);
  };
  auto body = [&](int b) {
    const _Float16* ldsK = &lds[b][0]    + lane * 8;
    const _Float16* ldsV = &lds[b][4096] + lane * 8;
    f32x4 sA[4], sB[4];
    __builtin_amdgcn_s_setprio(1);
#pragma unroll
    for (int c = 0; c < 4; ++c) {
      half8 k0 = *(const half8*)(ldsK + c*1024);
      half8 k1 = *(const half8*)(ldsK + c*1024 + 512);
      f32x4 tA = {}; tA = mfma16(k0, qa0, tA); tA = mfma16(k1, qa1, tA); sA[c] = tA;
      f32x4 tB = {}; tB = mfma16(k0, qb0, tB); tB = mfma16(k1, qb1, tB); sB[c] = tB;
    }
    __builtin_amdgcn_s_setprio(0);
    // raw v_exp_f32 (log2-domain, |s| small -> no clamp needed) + packed cvt
    H8U a0, a1, b0, b1;
#pragma unroll
    for (int c = 0; c < 4; ++c) {
      float eA0 = __builtin_amdgcn_exp2f(sA[c][0]);
      float eA1 = __builtin_amdgcn_exp2f(sA[c][1]);
      float eA2 = __builtin_amdgcn_exp2f(sA[c][2]);
      float eA3 = __builtin_amdgcn_exp2f(sA[c][3]);
      float eB0 = __builtin_amdgcn_exp2f(sB[c][0]);
      float eB1 = __builtin_amdgcn_exp2f(sB[c][1]);
      float eB2 = __builtin_amdgcn_exp2f(sB[c][2]);
      float eB3 = __builtin_amdgcn_exp2f(sB[c][3]);
      H8U* da = (c < 2) ? &a0 : &a1;
      H8U* db = (c < 2) ? &b0 : &b1;
      int base = (c & 1) * 2;
      da->h2[base]     = __builtin_amdgcn_cvt_pkrtz(eA0, eA1);
      da->h2[base + 1] = __builtin_amdgcn_cvt_pkrtz(eA2, eA3);
      db->h2[base]     = __builtin_amdgcn_cvt_pkrtz(eB0, eB1);
      db->h2[base + 1] = __builtin_amdgcn_cvt_pkrtz(eB2, eB3);
    }
    __builtin_amdgcn_s_setprio(1);
#pragma unroll
    for (int cc = 0; cc < 4; ++cc) {
      half8 v0 = *(const half8*)(ldsV + cc*1024);
      half8 v1 = *(const half8*)(ldsV + cc*1024 + 512);
      accA[cc] = mfma16(v0, a0.h8, accA[cc]); accA[cc] = mfma16(v1, a1.h8, accA[cc]);
      accB[cc] = mfma16(v0, b0.h8, accB[cc]); accB[cc] = mfma16(v1, b1.h8, accB[cc]);
    }
    acclA = mfma16(ones, a0.h8, acclA); acclA = mfma16(ones, a1.h8, acclA);
    acclB = mfma16(ones, b0.h8, acclB); acclB = mfma16(ones, b1.h8, acclB);
    __builtin_amdgcn_s_setprio(0);
  };

  // T4 counted-vmcnt pipeline: prefetch stays in flight ACROSS the barrier;
  // no vmcnt(0) drain in the main loop.
  stage(0, 0);
#pragma unroll 1
  for (int t = 0; t < 9; ++t) {
    if (t < 8) {
      stage(t + 1, (t + 1) & 1);                       // 4 loads in flight
      asm volatile("s_waitcnt vmcnt(4)" ::: "memory"); // own stage(t) landed
    } else {
      asm volatile("s_waitcnt vmcnt(0)" ::: "memory");
    }
    __builtin_amdgcn_sched_barrier(0);
    __builtin_amdgcn_s_barrier();        // all waves' stage(t) landed
    __builtin_amdgcn_sched_barrier(0);
    body(t & 1);
    __builtin_amdgcn_sched_barrier(0);
    __builtin_amdgcn_s_barrier();        // all readers of buf done before overwrite
  }

  // epilogue: accl[0] is the full per-query denom (identical across r and g4)
  float invA = 1.0f / acclA[0];
  float invB = 1.0f / acclB[0];
  _Float16* Oa = Opart + (((size_t)chunk * 16 + pair) * N_TOK + n0 + lr) * 64;
  _Float16* Ob = Oa + 16 * 64;
#pragma unroll
  for (int cc = 0; cc < 4; ++cc) {
    half4 ha, hb;
#pragma unroll
    for (int r = 0; r < 4; ++r) {
      ha[r] = (_Float16)(accA[cc][r] * invA);
      hb[r] = (_Float16)(accB[cc][r] * invB);
    }
    *(half4*)(Oa + 16*cc + 4*g4) = ha;
    *(half4*)(Ob + 16*cc + 4*g4) = hb;
  }
  if (g4 == 0) {
    Lpart[((size_t)chunk * 16 + pair) * N_TOK + n0 + lr] = acclA[0];
    Lpart[((size_t)chunk * 16 + pair) * N_TOK + n0 + 16 + lr] = acclB[0];
  }
}

// ---- kernel 5: merge split-K chunks (l-weighted), weight by c_g, sum over gk ----
__global__ __launch_bounds__(256) void k_combine(
    const _Float16* __restrict__ Opart, const float* __restrict__ Lpart,
    float* __restrict__ out) {
  int gid = blockIdx.x * 256 + threadIdx.x;   // 73728 total
  int hd = gid / (N_TOK * 8);
  int rem = gid % (N_TOK * 8);
  int n = rem >> 3, db = (rem & 7) * 8;
  float acc[8] = {};
#pragma unroll
  for (int gk = 0; gk < 4; ++gk) {
    float cg = (((hd - gk) & 3) == 2) ? 2.0f : 1.0f;
    int pair = hd * 4 + gk;
    float la[4], lsum = 0.f;
#pragma unroll
    for (int ch = 0; ch < 4; ++ch) {
      la[ch] = Lpart[((size_t)ch * 16 + pair) * N_TOK + n];
      lsum += la[ch];
    }
    float rs = cg / lsum;
#pragma unroll
    for (int ch = 0; ch < 4; ++ch) {
      half8 v = *(const half8*)(Opart + (((size_t)ch * 16 + pair) * N_TOK + n) * 64 + db);
      float w = la[ch] * rs;
#pragma unroll
      for (int i = 0; i < 8; ++i) acc[i] += w * (float)v[i];
    }
  }
  float* dst = out + (size_t)n * OUTC + hd * 64 + db;
  float4 r0, r1;
  r0.x = acc[0]; r0.y = acc[1]; r0.z = acc[2]; r0.w = acc[3];
  r1.x = acc[4]; r1.y = acc[5]; r1.z = acc[6]; r1.w = acc[7];
  *(float4*)(dst)     = r0;
  *(float4*)(dst + 4) = r1;
}

extern "C" void kernel_launch(void* const* d_in, const int* in_sizes, int n_in,
                              void* d_out, int out_size, void* d_ws, size_t ws_size,
                              hipStream_t stream) {
  (void)in_sizes; (void)n_in; (void)out_size; (void)ws_size;
  const float* x  = (const float*)d_in[0];
  const float* Wq = (const float*)d_in[1];
  const float* bq = (const float*)d_in[2];
  const float* Wk = (const float*)d_in[3];
  const float* bk = (const float*)d_in[4];
  const float* Wv = (const float*)d_in[5];
  const float* bv = (const float*)d_in[6];

  char* ws = (char*)d_ws;
  _Float16* xh  = (_Float16*)(ws);              // 1,179,648 B (dead after k_proj)
  float*    Lp  = (float*)   (ws);              // reuses xh region (589,824 B)
  _Float16* Wh  = (_Float16*)(ws + 1179648);    //   393,216 B
  _Float16* Qh  = (_Float16*)(ws + 1572864);    // 1,179,648 B
  _Float16* KF  = (_Float16*)(ws + 2752512);    // 1,179,648 B (fragment-major)
  float*    VfT = (float*)   (ws + 3932160);    // 2,359,296 B
  _Float16* VF  = (_Float16*)(ws + 6291456);    // 1,179,648 B (fragment-major)
  _Float16* Op  = (_Float16*)(ws + 7471104);    // 9,437,184 B (ends 16,908,288)
  float* out = (float*)d_out;

  k_convert<<<dim3(576), dim3(256), 0, stream>>>(x, Wq, Wk, Wv, xh, Wh);
  k_proj   <<<dim3(36, 4, 3), dim3(256), 0, stream>>>(xh, Wh, bq, bk, bv, Qh, KF, VfT);
  k_smooth <<<dim3(36, 4), dim3(256), 0, stream>>>(VfT, VF);
  k_flash  <<<dim3(18, 16, 4), dim3(256), 0, stream>>>(Qh, KF, VF, Op, Lp);
  k_combine<<<dim3(288), dim3(256), 0, stream>>>(Op, Lp, out);
}